// Round 7
// baseline (279.472 us; speedup 1.0000x reference)
//
#include <hip/hip_runtime.h>

// Round 7: f-split chains with weights streamed from GLOBAL into registers.
//
// Rounds 4-6 post-mortem established: LDS does not dedupe broadcast lane
// requests -- every batch re-reads its site's 512B of weights through the
// ~110 B/cyc LDS pipe (25 MB/CU total -> >=80us floor for any LDS-weight
// scheme). Fix: weights via VMEM (1 line-lookup/instr, L1-broadcast), landing
// in per-lane registers where they are reused by all 32 batches of the wave.
//
//  - 2 lanes per (batch,side) chain; lane f owns phi_f. Exchange via
//    v_mov_dpp quad_perm(1,0,3,2) -- zero DS instructions (round-6 proven).
//  - Per site, lane loads its 64-float f-half as 16 dwordx4 at base+f*32B
//    (divergent address -> vector loads). Register double-buffer wA/wB:
//    prefetch for site k+2 issued at site k -> ~400 cyc slack vs ~200 L1/L2.
//  - x staged through LDS, double-buffered 16-site chunks ([site][batch],
//    2-way reads = free). LDS traffic now ~2% of its BW.
//  - Single fused kernel: block 256 = 64 batches x {left,right} x 2 lanes;
//    waves 0-1 left, 2-3 right. Grid 256 = 1 block/CU. Label combine at end.

#define NSITES 784
#define DIM    8
#define ODIM   10
#define LABEL  392

__device__ __forceinline__ float dpp_swap(float x) {
    int i = __float_as_int(x);
    i = __builtin_amdgcn_update_dpp(0, i, 0xB1, 0xF, 0xF, true);  // quad_perm [1,0,3,2]
    return __int_as_float(i);
}

__global__ __launch_bounds__(256, 1) void mps_fused(
    const float* __restrict__ x,      // [B, N]
    const float* __restrict__ w0,     // [2, 8]
    const float* __restrict__ Wl,     // [391][d][f][e]
    const float* __restrict__ wlab,   // [8][2][8][10]
    const float* __restrict__ Wr,     // [390][d][f][e]
    const float* __restrict__ wlast,  // [8][2]
    float* __restrict__ out)          // [B, 10]
{
    __shared__ float xbl[2][16][64];   // x chunks, [buf][site-slot][batch]
    __shared__ float xbr[2][16][64];
    __shared__ float wlsh[1280];
    __shared__ float vls[64][8];
    __shared__ float rvs[64][8];

    const int tid  = threadIdx.x;
    const int wave = tid >> 6;
    const int lane = tid & 63;
    const int side = wave >> 1;                      // 0 = left, 1 = right
    const int f    = lane & 1;                       // phi-half owned
    const int g    = (wave & 1) * 32 + (lane >> 1);  // batch in block 0..63
    const int b0   = blockIdx.x * 64;

    // ---- cooperative x staging (all threads, both sides) ----
    const int sg = tid & 63;        // batch
    const int sk = tid >> 6;        // float4 slot (4 sites)
    float4 xlr, xrr;
    auto stageA = [&](int w) {      // global -> regs; left chunk w, right chunk 48-w
        xlr = *(const float4*)(x + (size_t)(b0 + sg) * NSITES + 16 * w + 4 * sk);
        xrr = *(const float4*)(x + (size_t)(b0 + sg) * NSITES + 16 * (48 - w) + 4 * sk);
    };
    auto stageB = [&](int buf) {    // regs -> LDS
        xbl[buf][4 * sk + 0][sg] = xlr.x;  xbl[buf][4 * sk + 1][sg] = xlr.y;
        xbl[buf][4 * sk + 2][sg] = xlr.z;  xbl[buf][4 * sk + 3][sg] = xlr.w;
        xbr[buf][4 * sk + 0][sg] = xrr.x;  xbr[buf][4 * sk + 1][sg] = xrr.y;
        xbr[buf][4 * sk + 2][sg] = xrr.z;  xbr[buf][4 * sk + 3][sg] = xrr.w;
    };

    // ---- per-wave weight stream state ----
    float wA[64], wB[64];
    auto loadW = [&](float* dst, const float* src) {
        #pragma unroll
        for (int d = 0; d < 8; ++d) {
            *(float4*)(dst + 8 * d)     = *(const float4*)(src + 16 * d);
            *(float4*)(dst + 8 * d + 4) = *(const float4*)(src + 16 * d + 4);
        }
    };
    const int   WSTEP = side ? -128 : 128;
    const float* wpre = (side ? Wr + 389 * 128 : Wl) + f * 8;   // site k=0

    loadW(wA, wpre);  wpre += WSTEP;     // k=0 -> wA
    loadW(wB, wpre);  wpre += WSTEP;     // k=1 -> wB (in flight)

    // ---- boundary init (both lanes of a pair hold full v) ----
    float v[8];
    if (side == 0) {
        const float p0 = x[(size_t)(b0 + g) * NSITES];
        #pragma unroll
        for (int e = 0; e < 8; ++e) v[e] = fmaf(1.0f - p0, w0[e], p0 * w0[8 + e]);
    } else {
        const float pN = x[(size_t)(b0 + g) * NSITES + NSITES - 1];
        #pragma unroll
        for (int d = 0; d < 8; ++d) v[d] = fmaf(1.0f - pN, wlast[2 * d], pN * wlast[2 * d + 1]);
    }

// one chain step: compute from W regs + x slot, then prefetch 2-ahead into W
#define STEP_L(W, XS, SLOT, PF)                                              \
    {                                                                        \
        const float p  = (XS)[(SLOT) * 64 + g];                              \
        const float sf = f ? p : 1.0f - p;                                   \
        float acc[8];                                                        \
        _Pragma("unroll") for (int e = 0; e < 8; ++e) acc[e] = v[0] * (W)[e];\
        _Pragma("unroll") for (int d = 1; d < 8; ++d)                        \
            _Pragma("unroll") for (int e = 0; e < 8; ++e)                    \
                acc[e] = fmaf(v[d], (W)[8 * d + e], acc[e]);                 \
        _Pragma("unroll") for (int i = 0; i < 8; ++i) {                      \
            const float t = sf * acc[i];                                     \
            v[i] = t + dpp_swap(t);                                          \
        }                                                                    \
        if (PF) { loadW((W), wpre); wpre += WSTEP; }                         \
    }
#define STEP_R(W, XS, SLOT, PF)                                              \
    {                                                                        \
        const float p  = (XS)[(SLOT) * 64 + g];                              \
        const float sf = f ? p : 1.0f - p;                                   \
        float acc[8];                                                        \
        _Pragma("unroll") for (int d = 0; d < 8; ++d) acc[d] = v[0] * (W)[8 * d];\
        _Pragma("unroll") for (int e = 1; e < 8; ++e)                        \
            _Pragma("unroll") for (int d = 0; d < 8; ++d)                    \
                acc[d] = fmaf(v[e], (W)[8 * d + e], acc[d]);                 \
        _Pragma("unroll") for (int i = 0; i < 8; ++i) {                      \
            const float t = sf * acc[i];                                     \
            v[i] = t + dpp_swap(t);                                          \
        }                                                                    \
        if (PF) { loadW((W), wpre); wpre += WSTEP; }                         \
    }

    // ---- prologue: stage chunk for window 0 + wlab ----
    stageA(0); stageB(0);
    for (int k2 = tid; k2 < 320; k2 += 256)
        *(float4*)&wlsh[k2 * 4] = *(const float4*)&wlab[k2 * 4];
    __syncthreads();

    // ---- window 0: 15 sites (left slots 1..15 / right slots 14..0) ----
    stageA(1);
    if (side == 0) {
        const float* xS = &xbl[0][0][0];
        STEP_L(wA, xS, 1, 1)
        #pragma unroll 2
        for (int jj = 0; jj < 7; ++jj) {
            STEP_L(wB, xS, 2 * jj + 2, 1)
            STEP_L(wA, xS, 2 * jj + 3, 1)
        }
    } else {
        const float* xS = &xbr[0][0][0];
        STEP_R(wA, xS, 14, 1)
        #pragma unroll 2
        for (int jj = 0; jj < 7; ++jj) {
            STEP_R(wB, xS, 13 - 2 * jj, 1)
            STEP_R(wA, xS, 12 - 2 * jj, 1)
        }
    }
    stageB(1);
    __syncthreads();

    // ---- windows 1..23: 16 sites each ----
    #pragma unroll 1
    for (int w = 1; w <= 23; ++w) {
        stageA(w + 1);
        const int buf = w & 1;
        if (side == 0) {
            const float* xS = &xbl[buf][0][0];
            #pragma unroll 2
            for (int jj = 0; jj < 8; ++jj) {
                STEP_L(wB, xS, 2 * jj, 1)
                STEP_L(wA, xS, 2 * jj + 1, 1)
            }
        } else {
            const float* xS = &xbr[buf][0][0];
            #pragma unroll 2
            for (int jj = 0; jj < 8; ++jj) {
                STEP_R(wB, xS, 15 - 2 * jj, 1)
                STEP_R(wA, xS, 14 - 2 * jj, 1)
            }
        }
        stageB(buf ^ 1);
        __syncthreads();
    }

    // ---- window 24 (buf 0): left 8 sites (slots 0..7), right 7 (slots 15..9)
    if (side == 0) {
        const float* xS = &xbl[0][0][0];
        #pragma unroll 2
        for (int jj = 0; jj < 3; ++jj) {        // sites k=383..388, prefetch valid
            STEP_L(wB, xS, 2 * jj, 1)
            STEP_L(wA, xS, 2 * jj + 1, 1)
        }
        STEP_L(wB, xS, 6, 0)
        STEP_L(wA, xS, 7, 0)
    } else {
        const float* xS = &xbr[0][0][0];
        STEP_R(wB, xS, 15, 1)
        STEP_R(wA, xS, 14, 1)
        STEP_R(wB, xS, 13, 1)
        STEP_R(wA, xS, 12, 1)
        STEP_R(wB, xS, 11, 1)
        STEP_R(wA, xS, 10, 0)
        STEP_R(wB, xS, 9, 0)
    }

    // ---- deposit boundary vectors (f lanes hold identical v; f==0 writes)
    if (f == 0) {
        float* dst = (side == 0) ? &vls[g][0] : &rvs[g][0];
        *(float4*)&dst[0] = make_float4(v[0], v[1], v[2], v[3]);
        *(float4*)&dst[4] = make_float4(v[4], v[5], v[6], v[7]);
    }
    __syncthreads();

    // ---- fused label-site combine: 64 batches x 10 outputs ----
    #pragma unroll
    for (int rr = 0; rr < 3; ++rr) {
        const int idx = tid + 256 * rr;
        if (idx < 640) {
            const int bi = idx / 10;
            const int o  = idx - bi * 10;
            const float p = x[(size_t)(b0 + bi) * NSITES + LABEL];
            const float q = 1.0f - p;
            float acc = 0.0f;
            #pragma unroll
            for (int d = 0; d < 8; ++d) {
                #pragma unroll
                for (int e = 0; e < 8; ++e) {
                    const float m = fmaf(p, wlsh[(16 * d + 8 + e) * 10 + o],
                                         q * wlsh[(16 * d + e) * 10 + o]);
                    acc = fmaf(vls[bi][d] * rvs[bi][e], m, acc);
                }
            }
            out[(size_t)(b0 + bi) * ODIM + o] = acc;
        }
    }
#undef STEP_L
#undef STEP_R
}

extern "C" void kernel_launch(void* const* d_in, const int* in_sizes, int n_in,
                              void* d_out, int out_size, void* d_ws, size_t ws_size,
                              hipStream_t stream) {
    const float* x     = (const float*)d_in[0];
    const float* w0    = (const float*)d_in[1];
    const float* Wl    = (const float*)d_in[2];
    const float* wlab  = (const float*)d_in[3];
    const float* Wr    = (const float*)d_in[4];
    const float* wlast = (const float*)d_in[5];
    float* out = (float*)d_out;

    mps_fused<<<256, 256, 0, stream>>>(x, w0, Wl, wlab, Wr, wlast, out);
}